// Round 5
// baseline (620.107 us; speedup 1.0000x reference)
//
#include <hip/hip_runtime.h>

#define NVOX 400000
#define K27 27
#define EPS_ 1e-5f

typedef short short8 __attribute__((ext_vector_type(8)));
typedef float floatx4 __attribute__((ext_vector_type(4)));
typedef unsigned int uintx4 __attribute__((ext_vector_type(4)));

// round-to-nearest-even fp32 -> bf16, packed pair (a low 16, b high 16)
__device__ __forceinline__ unsigned int pack2bf(float a, float b) {
    unsigned int ua = __builtin_bit_cast(unsigned int, a);
    unsigned int ub = __builtin_bit_cast(unsigned int, b);
    ua += 0x7fffu + ((ua >> 16) & 1u);
    ub += 0x7fffu + ((ub >> 16) & 1u);
    return (ua >> 16) | (ub & 0xffff0000u);
}

// async 16B global->LDS (direct, no VGPR round-trip).
// global source is PER-LANE; LDS dest is wave-uniform base + lane*16.
__device__ __forceinline__ void gload_lds16(const void* g, void* l) {
    __builtin_amdgcn_global_load_lds(
        (const __attribute__((address_space(1))) void*)g,
        (__attribute__((address_space(3))) void*)l, 16, 0, 0);
}

// blocks [0, fb): fp32->bf16 feature conversion (32 elems/thread)
// blocks [fb, fb+32): W[k][ci][co] -> wt[k][co][ci] bf16
// block  fb+32: zero the 128 stats accumulators + the zero-row
__global__ void prep_kernel(const float* __restrict__ w,
                            const float* __restrict__ feat,
                            unsigned short* __restrict__ feat_bf,
                            unsigned short* __restrict__ wt,
                            float* __restrict__ sums,
                            float* __restrict__ zrow,
                            int fb) {
    const int b = blockIdx.x;
    const int t = threadIdx.x;
    if (b < fb) {
#pragma unroll
        for (int r = 0; r < 4; ++r) {
            const int i0 = b * 8192 + r * 2048 + t * 8;
            const floatx4* s = (const floatx4*)(feat + i0);
            const floatx4 f0 = s[0], f1 = s[1];
            uintx4 v;
            v[0] = pack2bf(f0[0], f0[1]); v[1] = pack2bf(f0[2], f0[3]);
            v[2] = pack2bf(f1[0], f1[1]); v[3] = pack2bf(f1[2], f1[3]);
            *(uintx4*)(feat_bf + i0) = v;
        }
    } else if (b < fb + 32) {
        for (int g = (b - fb) * 256 + t; g < K27 * 64 * 64; g += 32 * 256) {
            const int k = g >> 12, r = g & 4095, co = r >> 6, ci = r & 63;
            unsigned int u =
                __builtin_bit_cast(unsigned int, w[(k << 12) + (ci << 6) + co]);
            u += 0x7fffu + ((u >> 16) & 1u);
            wt[g] = (unsigned short)(u >> 16);
        }
    } else {
        if (t < 128) sums[t] = 0.0f;
        else if (zrow && t < 136) zrow[t - 128] = 0.0f;
    }
}

// 64 rows x 64 out-ch per block (6250 blocks), 128 threads = 2 waves, wave
// tile M=32 x N=64 -> 2x4 mfma_f32_16x16x32_bf16 per kb (acc 32 AGPR).
//
// R11: back to R8's PROVEN sync (__syncthreads-drained double buffer; R9/
// R10's counted-vmcnt schedules both failed correctness -- abandoned as
// unverifiable without disasm). Attack latency via STREAMS instead:
//  * M=64 blocks, 2 waves: per-block LDS A-dbuf 2x8KB. B LDS tiles are
//    DELETED -- B fragments are 16 contiguous bytes wt[k][nt*16+m][kb*32+
//    q*8..] read directly global->VGPR (8KB/step slice, L1/L2-resident,
//    shared by every block chip-wide; no swizzle needed).
//  * idx preamble restored (27x64 ints in LDS, one coalesced load):
//    per-step idx read is a ~120cy ds_read instead of a ~200-900cy global
//    load at the head of the serial chain (R8's hidden cost).
//  * LDS total ~23.8KB -> 6 blocks/CU = 6 independent barrier-streams
//    (R8: 2.25-3). The per-step vmcnt(0) drain stall of one block
//    overlaps other blocks' compute -- pure TLP, no sync-semantics risk.
//  * gather side unchanged from R8 (correctness-proven): gload_lds16,
//    XOR chunk swizzle applied to the per-lane GLOBAL source + linear LDS
//    dest (g21); inactive rows redirected to a zero-row.
template <bool BF16FEAT>
__launch_bounds__(128)
__global__ void conv_mfma(const float* __restrict__ feat,
                          const unsigned short* __restrict__ feat_bf,
                          const int* __restrict__ nmap,
                          const unsigned short* __restrict__ wt,
                          const unsigned short* __restrict__ zrow,
                          float* __restrict__ out,
                          float* __restrict__ sums) {
    __shared__ __align__(16) unsigned short a_tile[2][64 * 64];  // 2x8 KB
    __shared__ int idx_lds[K27 * 64];                            // 6.75 KB
    __shared__ float cstat[128];

    const int tid  = threadIdx.x;
    const int wv   = tid >> 6;
    const int lane = tid & 63;
    const int m    = lane & 15;
    const int q    = lane >> 4;

    // bijective XCD-chunked remap (m204): each XCD gets a contiguous range
    const int nwg = gridDim.x;
    const int q8 = nwg >> 3, r8 = nwg & 7;
    const int xcd = blockIdx.x & 7, lin = blockIdx.x >> 3;
    const int wg =
        (xcd < r8 ? xcd * (q8 + 1) : r8 * (q8 + 1) + (xcd - r8) * q8) + lin;
    const int base = wg * 64;

    // ---- preamble: cache nmap[k][base..base+64) in LDS (coalesced)
    for (int j = tid; j < K27 * 64; j += 128)
        idx_lds[j] = nmap[(size_t)(j >> 6) * NVOX + base + (j & 63)];
    cstat[tid] = 0.0f;
    __syncthreads();  // idx + cstat visible

    // staging geometry: thread covers A chunks c = j*128 + wv*64 + lane
    // (j<4): row = c>>3 = j*16 + wv*8 + (lane>>3), slot-col = lane&7.
    // Since row%8 == lane>>3, the global-source XOR swizzle
    // gcx = (lane&7) ^ (lane>>3) is j-independent. Slot (row,s) then holds
    // source chunk s ^ (row&7); the read side XORs the same way.
    const int rsub = lane >> 3;
    const int gcx  = (lane & 7) ^ rsub;
    int arow[4];
#pragma unroll
    for (int j = 0; j < 4; ++j) arow[j] = j * 16 + wv * 8 + rsub;

    int row_a[2];
#pragma unroll
    for (int mt = 0; mt < 2; ++mt) row_a[mt] = wv * 32 + mt * 16 + m;

    floatx4 acc[2][4];
#pragma unroll
    for (int mt = 0; mt < 2; ++mt)
#pragma unroll
        for (int nt = 0; nt < 4; ++nt)
            acc[mt][nt] = (floatx4){0.f, 0.f, 0.f, 0.f};

// stage A tile kk into buffer bufidx: 4 gload_lds16 per thread; idx from
// LDS (ds_read broadcast); inactive rows pull from the zero-row.
#define STAGE_A(bufidx, kk)                                                   \
    do {                                                                      \
        int ixr[4];                                                           \
        _Pragma("unroll") for (int j = 0; j < 4; ++j)                         \
            ixr[j] = idx_lds[(kk) * 64 + arow[j]];                            \
        _Pragma("unroll") for (int j = 0; j < 4; ++j) {                       \
            const unsigned short* src =                                       \
                (ixr[j] >= 0) ? feat_bf + (size_t)ixr[j] * 64 + gcx * 8       \
                              : zrow;                                         \
            gload_lds16(src, a_tile[bufidx] + (j * 128 + wv * 64) * 8);       \
        }                                                                     \
    } while (0)

// compute tile kk from buffer bufidx; B fragments direct from global
// (16 contiguous bytes each, no swizzle).
#define COMPUTE(bufidx, kk)                                                   \
    do {                                                                      \
        const unsigned short* bp = wt + (size_t)(kk) * 4096 + m * 64 + q * 8; \
        _Pragma("unroll") for (int kb = 0; kb < 2; ++kb) {                    \
            short8 af[2], bfr[4];                                             \
            _Pragma("unroll") for (int mt = 0; mt < 2; ++mt)                  \
                af[mt] = *(const short8*)(                                    \
                    a_tile[bufidx] +                                          \
                    (row_a[mt] * 8 + ((kb * 4 + q) ^ (row_a[mt] & 7))) * 8);  \
            _Pragma("unroll") for (int nt = 0; nt < 4; ++nt)                  \
                bfr[nt] = *(const short8*)(bp + nt * 1024 + kb * 32);         \
            _Pragma("unroll") for (int mt = 0; mt < 2; ++mt)                  \
                _Pragma("unroll") for (int nt = 0; nt < 4; ++nt)              \
                    acc[mt][nt] = __builtin_amdgcn_mfma_f32_16x16x32_bf16(    \
                        af[mt], bfr[nt], acc[mt][nt], 0, 0, 0);               \
        }                                                                     \
    } while (0)

    if constexpr (BF16FEAT) {
        STAGE_A(0, 0);
        __syncthreads();  // tile 0 resident
        for (int kk = 0; kk < K27; kk += 2) {
            if (kk + 1 < K27) STAGE_A(1, kk + 1);  // async into buf1
            COMPUTE(0, kk);                        // tile kk from buf0
            __syncthreads();                       // drain kk+1; reads done
            if (kk + 1 >= K27) break;
            if (kk + 2 < K27) STAGE_A(0, kk + 2);
            COMPUTE(1, kk + 1);
            __syncthreads();
        }
    } else {
        // fallback: fp32 gather + in-register pack, single-buffered staging
        for (int kk = 0; kk < K27; ++kk) {
            short8 areg[4];
            int farow[4], fslot[4];
#pragma unroll
            for (int j = 0; j < 4; ++j) {
                const int c = tid + 128 * j;
                farow[j] = c >> 3;
                fslot[j] = c & 7;
                const int ix = idx_lds[kk * 64 + farow[j]];
                areg[j] = (short8){0, 0, 0, 0, 0, 0, 0, 0};
                if (ix >= 0) {
                    const int gcs = fslot[j] ^ (farow[j] & 7);
                    const float* fp = feat + (size_t)ix * 64 + gcs * 8;
                    const floatx4 f0 = *(const floatx4*)fp;
                    const floatx4 f1 = *(const floatx4*)(fp + 4);
                    uintx4 v;
                    v[0] = pack2bf(f0[0], f0[1]); v[1] = pack2bf(f0[2], f0[3]);
                    v[2] = pack2bf(f1[0], f1[1]); v[3] = pack2bf(f1[2], f1[3]);
                    areg[j] = __builtin_bit_cast(short8, v);
                }
            }
            __syncthreads();  // previous iter's reads done
#pragma unroll
            for (int j = 0; j < 4; ++j)
                *(short8*)(a_tile[0] + (farow[j] * 8 + fslot[j]) * 8) =
                    areg[j];
            __syncthreads();
            COMPUTE(0, kk);
        }
    }
#undef STAGE_A
#undef COMPUTE

    // epilogue: store (C/D: col=lane&15, row=q*4+reg — m89-verified) + stats
#pragma unroll
    for (int nt = 0; nt < 4; ++nt) {
        const int col = nt * 16 + m;
        float s = 0.f, s2 = 0.f;
#pragma unroll
        for (int mt = 0; mt < 2; ++mt) {
            const int row0 = base + wv * 32 + mt * 16 + q * 4;
#pragma unroll
            for (int i = 0; i < 4; ++i) {
                const float v = acc[mt][nt][i];
                s += v;
                s2 += v * v;
                out[(size_t)(row0 + i) * 64 + col] = v;
            }
        }
        atomicAdd(&cstat[col], s);
        atomicAdd(&cstat[64 + col], s2);
    }
    __syncthreads();
    if (tid < 128) atomicAdd(&sums[tid], cstat[tid]);
}

__global__ void bn_apply(float* __restrict__ out, const float* __restrict__ sums,
                         const float* __restrict__ gamma,
                         const float* __restrict__ beta) {
    __shared__ float sc[64];
    __shared__ float sh[64];
    const int tid = threadIdx.x;
    if (tid < 64) {
        const float inv_n = 1.0f / (float)NVOX;
        const float mean = sums[tid] * inv_n;
        const float var  = sums[64 + tid] * inv_n - mean * mean;
        const float g    = gamma[tid] * rsqrtf(var + EPS_);
        sc[tid] = g;
        sh[tid] = beta[tid] - mean * g;
    }
    __syncthreads();
    const int cg = (tid & 15) * 4;
    floatx4 scale, shift;
#pragma unroll
    for (int j = 0; j < 4; ++j) {
        scale[j] = sc[cg + j];
        shift[j] = sh[cg + j];
    }
    floatx4* p = (floatx4*)out;
    const int total4 = NVOX * 16;
    for (int i = blockIdx.x * 256 + tid; i < total4; i += gridDim.x * 256) {
        floatx4 v = p[i] * scale + shift;
#pragma unroll
        for (int j = 0; j < 4; ++j) v[j] = v[j] > 0.f ? v[j] : 0.f;
        p[i] = v;
    }
}

extern "C" void kernel_launch(void* const* d_in, const int* in_sizes, int n_in,
                              void* d_out, int out_size, void* d_ws, size_t ws_size,
                              hipStream_t stream) {
    const float* feat  = (const float*)d_in[0];
    const int*   nmap  = (const int*)d_in[1];
    const float* w     = (const float*)d_in[2];
    const float* gamma = (const float*)d_in[3];
    const float* beta  = (const float*)d_in[4];
    float* out = (float*)d_out;

    const size_t FEATB = (size_t)NVOX * 64 * 2;      // 51,200,000
    const size_t WTB   = (size_t)K27 * 64 * 64 * 2;  //    221,184
    const int conv_blocks = NVOX / 64;               // 6250 exactly

    if (ws_size >= FEATB + WTB + 512 + 128) {
        unsigned short* feat_bf = (unsigned short*)d_ws;
        unsigned short* wt      = (unsigned short*)((char*)d_ws + FEATB);
        float* sums             = (float*)((char*)d_ws + FEATB + WTB);
        float* zrow             = (float*)((char*)d_ws + FEATB + WTB + 512);
        prep_kernel<<<dim3(3158), dim3(256), 0, stream>>>(
            w, feat, feat_bf, wt, sums, zrow, 3125);
        conv_mfma<true><<<dim3(conv_blocks), dim3(128), 0, stream>>>(
            feat, feat_bf, nmap, wt, (const unsigned short*)zrow, out, sums);
        bn_apply<<<dim3(1024), dim3(256), 0, stream>>>(out, sums, gamma, beta);
    } else {
        // fallback: fp32 gather + in-register pack (no feature buffer)
        unsigned short* wt = (unsigned short*)d_ws;
        float* sums        = (float*)((char*)d_ws + WTB);
        prep_kernel<<<dim3(33), dim3(256), 0, stream>>>(
            w, feat, nullptr, wt, sums, nullptr, 0);
        conv_mfma<false><<<dim3(conv_blocks), dim3(128), 0, stream>>>(
            feat, nullptr, nmap, wt, nullptr, out, sums);
        bn_apply<<<dim3(1024), dim3(256), 0, stream>>>(out, sums, gamma, beta);
    }
}